// Round 4
// baseline (746.183 us; speedup 1.0000x reference)
//
#include <hip/hip_runtime.h>
#include <hip/hip_bf16.h>
#include <stdint.h>

typedef __bf16 bf16x8 __attribute__((ext_vector_type(8)));
typedef float f32x4 __attribute__((ext_vector_type(4)));
typedef unsigned short u16x8 __attribute__((ext_vector_type(8)));

// float -> bf16 round-to-nearest-even (bit trick; inputs are finite here)
__device__ inline unsigned short f2bf_rne(float f) {
  unsigned int u = __float_as_uint(f);
  u += 0x7fffu + ((u >> 16) & 1u);
  return (unsigned short)(u >> 16);
}

// w = mu + eps * exp(0.5*lv), packed bf16. 8 elems/thread, 16B store.
__global__ __launch_bounds__(256) void prep_weight(
    const float4* __restrict__ mu, const float4* __restrict__ lv,
    const float4* __restrict__ eps, u16x8* __restrict__ wbf, int n8) {
  int i = blockIdx.x * 256 + threadIdx.x;
  if (i >= n8) return;
  float4 m0 = mu[2 * i], m1 = mu[2 * i + 1];
  float4 v0 = lv[2 * i], v1 = lv[2 * i + 1];
  float4 e0 = eps[2 * i], e1 = eps[2 * i + 1];
  u16x8 p;
  p[0] = f2bf_rne(m0.x + e0.x * __expf(0.5f * v0.x));
  p[1] = f2bf_rne(m0.y + e0.y * __expf(0.5f * v0.y));
  p[2] = f2bf_rne(m0.z + e0.z * __expf(0.5f * v0.z));
  p[3] = f2bf_rne(m0.w + e0.w * __expf(0.5f * v0.w));
  p[4] = f2bf_rne(m1.x + e1.x * __expf(0.5f * v1.x));
  p[5] = f2bf_rne(m1.y + e1.y * __expf(0.5f * v1.y));
  p[6] = f2bf_rne(m1.z + e1.z * __expf(0.5f * v1.z));
  p[7] = f2bf_rne(m1.w + e1.w * __expf(0.5f * v1.w));
  wbf[i] = p;
}

__global__ __launch_bounds__(256) void prep_x(
    const float4* __restrict__ x, u16x8* __restrict__ xbf, int n8) {
  int i = blockIdx.x * 256 + threadIdx.x;
  if (i >= n8) return;
  float4 m0 = x[2 * i], m1 = x[2 * i + 1];
  u16x8 p;
  p[0] = f2bf_rne(m0.x); p[1] = f2bf_rne(m0.y);
  p[2] = f2bf_rne(m0.z); p[3] = f2bf_rne(m0.w);
  p[4] = f2bf_rne(m1.x); p[5] = f2bf_rne(m1.y);
  p[6] = f2bf_rne(m1.z); p[7] = f2bf_rne(m1.w);
  xbf[i] = p;
}

// C[M,N] = A[M,K]*B[N,K]^T + bias(N). 256x128 block tile, BK=64, 512 thr
// (8 waves 4Mx2N, wave tile 64x64 = 4x4 frags of 16x16x32, same geometry as
// the R0-verified kernel). Phased schedule (T3+T4+T5):
//   per K-tile: 4 phases x {2 stage loads for tile t+2 | ds_read next-phase
//   frags | 8 MFMA under setprio} + s_barrier. ph2 carries the counted wait
//   vmcnt(6): outstanding = t+1's 6 + t+2's 6 -> retires exactly tile t+1
//   (issued one full tile earlier => near-free). NEVER drains to 0 mid-loop.
//   ph3 pre-reads tile t+1's kk0 frags (legal: vmcnt(6)+barrier at ph2).
// Ring of 3 buffers: stage of t+2 writes buf (t+2)%3 = (t-1)%3, whose last
// reads finished before tile t-1's final barrier -> no WAR hazard.
// LDS rows = 64 elems = 128B with the R0-verified swizzle (measured ZERO
// bank conflicts): granule g of row r holds global granule g^(r&7); read
// pg = ((kk>>3)+gsel)^(mrow&7). (The BK=32 64B-row layout of R1-R3 showed a
// swizzle-independent 2^25 conflict count - abandoned.)
#define BM 256
#define BN 128
#define BK 64
#define NBUF 3

__global__ __launch_bounds__(512, 2) void gemm_bt_bias(
    const unsigned short* __restrict__ A,   // [M][K] bf16 bits
    const unsigned short* __restrict__ B,   // [N][K] bf16 bits
    const float* __restrict__ bmu, const float* __restrict__ blv,
    const float* __restrict__ beps,
    float* __restrict__ C, int M, int N, int K) {
  __shared__ __align__(16) unsigned short As[NBUF][BM * BK];  // 3 x 32 KB
  __shared__ __align__(16) unsigned short Bs[NBUF][BN * BK];  // 3 x 16 KB

  const int tid  = threadIdx.x;
  const int wave = tid >> 6;
  const int lane = tid & 63;
  const int wm = wave >> 1;   // 0..3 (M)
  const int wn = wave & 1;    // 0..1 (N)

  const int rowA0 = blockIdx.y * BM;
  const int rowB0 = blockIdx.x * BN;

  // staging: thread covers granule (tid&7) of row (tid>>3) per 64-row round.
  // global col = (granule ^ (row&7))*8 ; LDS deposit linear (base+lane*16B).
  const int srow = tid >> 3;                       // 0..63
  const int scol = ((tid & 7) ^ (srow & 7)) * 8;   // row&7 == srow&7 (rounds are 64-multiples)
  const unsigned short* gA0 = A + (size_t)(rowA0 + srow) * K + scol;
  const unsigned short* gA1 = gA0 + (size_t)64 * K;
  const unsigned short* gA2 = gA0 + (size_t)128 * K;
  const unsigned short* gA3 = gA0 + (size_t)192 * K;
  const unsigned short* gB0 = B + (size_t)(rowB0 + srow) * K + scol;
  const unsigned short* gB1 = gB0 + (size_t)64 * K;
  const int dep = wave * 512;  // wave-uniform deposit base (elems) per round

#define GLL(srcp, dstp)                                                     \
  __builtin_amdgcn_global_load_lds(                                         \
      (const __attribute__((address_space(1))) unsigned int*)(srcp),        \
      (__attribute__((address_space(3))) unsigned int*)(dstp), 16, 0, 0)

#define STAGE_A01(kt, b) do { const size_t ko_ = (size_t)(kt) * BK;          \
    GLL(gA0 + ko_, &As[b][dep]);                                             \
    GLL(gA1 + ko_, &As[b][4096 + dep]); } while (0)
#define STAGE_A23(kt, b) do { const size_t ko_ = (size_t)(kt) * BK;          \
    GLL(gA2 + ko_, &As[b][8192 + dep]);                                      \
    GLL(gA3 + ko_, &As[b][12288 + dep]); } while (0)
#define STAGE_B01(kt, b) do { const size_t ko_ = (size_t)(kt) * BK;          \
    GLL(gB0 + ko_, &Bs[b][dep]);                                             \
    GLL(gB1 + ko_, &Bs[b][4096 + dep]); } while (0)

  f32x4 acc[4][4];
#pragma unroll
  for (int i = 0; i < 4; ++i)
#pragma unroll
    for (int j = 0; j < 4; ++j)
      acc[i][j] = (f32x4){0.f, 0.f, 0.f, 0.f};

  const int mrow = lane & 15;   // fragment row
  const int gsel = lane >> 4;   // k-granule select 0..3
  const int pg0  = ((0 + gsel) ^ (mrow & 7)) * 8;   // kk=0  granule offset
  const int pg32 = ((4 + gsel) ^ (mrow & 7)) * 8;   // kk=32 granule offset
  const int abase = (wm * 64 + mrow) * BK;
  const int bbase = (wn * 64 + mrow) * BK;

#define RD_A(mi, pg, bufp) (*(const bf16x8*)&(bufp)[abase + (mi)*1024 + (pg)])
#define RD_B(ni, pg, bufp) (*(const bf16x8*)&(bufp)[bbase + (ni)*1024 + (pg)])

  // prologue: stage tiles 0 and 1 fully; wait tile 0 (tile 1's 6 stay in flight)
  STAGE_A01(0, 0); STAGE_A23(0, 0); STAGE_B01(0, 0);
  STAGE_A01(1, 1); STAGE_A23(1, 1); STAGE_B01(1, 1);
  asm volatile("s_waitcnt vmcnt(6)" ::: "memory");
  __builtin_amdgcn_s_barrier();
  __builtin_amdgcn_sched_barrier(0);

  bf16x8 bL[4], bH[4], a0, a1, a2, a3, t0, t1;
  {
    const unsigned short* as0 = &As[0][0];
    const unsigned short* bs0 = &Bs[0][0];
#pragma unroll
    for (int ni = 0; ni < 4; ++ni) bL[ni] = RD_B(ni, pg0, bs0);
    a0 = RD_A(0, pg0, as0);
    a1 = RD_A(1, pg0, as0);
  }

  const int NT = K / BK;   // 64
  int c = 0;
  for (int t = 0; t < NT; ++t) {
    const int n = (c + 1 < NBUF) ? c + 1 : 0;
    const int w = (c + 2 < NBUF) ? c + 2 : c + 2 - NBUF;  // buf for tile t+2
    const unsigned short* asc = &As[c][0];
    const unsigned short* bsc = &Bs[c][0];
    const bool pf = (t + 2 < NT);

    // ---- phase 0: MFMA mi{0,1} x kk0 ----
    if (pf) STAGE_A01(t + 2, w);
    a2 = RD_A(2, pg0, asc);
    a3 = RD_A(3, pg0, asc);
    __builtin_amdgcn_s_setprio(1);
#pragma unroll
    for (int ni = 0; ni < 4; ++ni) {
      acc[0][ni] = __builtin_amdgcn_mfma_f32_16x16x32_bf16(a0, bL[ni], acc[0][ni], 0, 0, 0);
      acc[1][ni] = __builtin_amdgcn_mfma_f32_16x16x32_bf16(a1, bL[ni], acc[1][ni], 0, 0, 0);
    }
    __builtin_amdgcn_s_setprio(0);
    __builtin_amdgcn_s_barrier();
    __builtin_amdgcn_sched_barrier(0);

    // ---- phase 1: MFMA mi{2,3} x kk0 ----
    if (pf) STAGE_A23(t + 2, w);
#pragma unroll
    for (int ni = 0; ni < 4; ++ni) bH[ni] = RD_B(ni, pg32, bsc);
    t0 = RD_A(0, pg32, asc);
    t1 = RD_A(1, pg32, asc);
    __builtin_amdgcn_s_setprio(1);
#pragma unroll
    for (int ni = 0; ni < 4; ++ni) {
      acc[2][ni] = __builtin_amdgcn_mfma_f32_16x16x32_bf16(a2, bL[ni], acc[2][ni], 0, 0, 0);
      acc[3][ni] = __builtin_amdgcn_mfma_f32_16x16x32_bf16(a3, bL[ni], acc[3][ni], 0, 0, 0);
    }
    __builtin_amdgcn_s_setprio(0);
    __builtin_amdgcn_s_barrier();
    __builtin_amdgcn_sched_barrier(0);

    // ---- phase 2: MFMA mi{0,1} x kk32 ; counted boundary wait ----
    if (pf) STAGE_B01(t + 2, w);
    a2 = RD_A(2, pg32, asc);
    a3 = RD_A(3, pg32, asc);
    __builtin_amdgcn_s_setprio(1);
#pragma unroll
    for (int ni = 0; ni < 4; ++ni) {
      acc[0][ni] = __builtin_amdgcn_mfma_f32_16x16x32_bf16(t0, bH[ni], acc[0][ni], 0, 0, 0);
      acc[1][ni] = __builtin_amdgcn_mfma_f32_16x16x32_bf16(t1, bH[ni], acc[1][ni], 0, 0, 0);
    }
    __builtin_amdgcn_s_setprio(0);
    if (pf) { asm volatile("s_waitcnt vmcnt(6)" ::: "memory"); }   // tile t+1 landed; t+2's 6 in flight
    else    { asm volatile("s_waitcnt vmcnt(0)" ::: "memory"); }   // tail (last 2 tiles only)
    __builtin_amdgcn_s_barrier();
    __builtin_amdgcn_sched_barrier(0);

    // ---- phase 3: MFMA mi{2,3} x kk32 ; pre-read tile t+1's kk0 frags ----
    if (t + 1 < NT) {
      const unsigned short* asn = &As[n][0];
      const unsigned short* bsn = &Bs[n][0];
#pragma unroll
      for (int ni = 0; ni < 4; ++ni) bL[ni] = RD_B(ni, pg0, bsn);
      a0 = RD_A(0, pg0, asn);
      a1 = RD_A(1, pg0, asn);
    }
    __builtin_amdgcn_s_setprio(1);
#pragma unroll
    for (int ni = 0; ni < 4; ++ni) {
      acc[2][ni] = __builtin_amdgcn_mfma_f32_16x16x32_bf16(a2, bH[ni], acc[2][ni], 0, 0, 0);
      acc[3][ni] = __builtin_amdgcn_mfma_f32_16x16x32_bf16(a3, bH[ni], acc[3][ni], 0, 0, 0);
    }
    __builtin_amdgcn_s_setprio(0);
    __builtin_amdgcn_s_barrier();
    __builtin_amdgcn_sched_barrier(0);

    c = n;
  }

  // Epilogue: C/D layout col=lane&15, row=(lane>>4)*4+reg (m89-verified).
  const int colq = lane & 15;
  const int rq4  = (lane >> 4) * 4;
#pragma unroll
  for (int ni = 0; ni < 4; ++ni) {
    const int col = rowB0 + wn * 64 + ni * 16 + colq;
    const float bias = bmu[col] + beps[col] * __expf(0.5f * blv[col]);
#pragma unroll
    for (int mi = 0; mi < 4; ++mi) {
      const int rbase = rowA0 + wm * 64 + mi * 16 + rq4;
#pragma unroll
      for (int r = 0; r < 4; ++r)
        C[(size_t)(rbase + r) * N + col] = acc[mi][ni][r] + bias;
    }
  }
#undef GLL
#undef STAGE_A01
#undef STAGE_A23
#undef STAGE_B01
#undef RD_A
#undef RD_B
}

extern "C" void kernel_launch(void* const* d_in, const int* in_sizes, int n_in,
                              void* d_out, int out_size, void* d_ws, size_t ws_size,
                              hipStream_t stream) {
  const float* x    = (const float*)d_in[0];
  const float* wmu  = (const float*)d_in[1];
  const float* wlv  = (const float*)d_in[2];
  const float* bmu  = (const float*)d_in[3];
  const float* blv  = (const float*)d_in[4];
  const float* weps = (const float*)d_in[5];
  const float* beps = (const float*)d_in[6];
  float* out = (float*)d_out;

  const int M = 8192, N = 4096, K = 4096;

  // workspace: xbf [M*K] bf16 (64 MB) then wbf [N*K] bf16 (32 MB)
  unsigned short* xbf = (unsigned short*)d_ws;
  unsigned short* wbf = xbf + (size_t)M * K;

  const int n8w = N * K / 8;
  prep_weight<<<n8w / 256, 256, 0, stream>>>(
      (const float4*)wmu, (const float4*)wlv, (const float4*)weps,
      (u16x8*)wbf, n8w);
  const int n8x = M * K / 8;
  prep_x<<<n8x / 256, 256, 0, stream>>>((const float4*)x, (u16x8*)xbf, n8x);

  dim3 grid(N / BN, M / BM);  // 32 x 32 = 1024 blocks
  gemm_bt_bias<<<grid, 512, 0, stream>>>(xbf, wbf, bmu, blv, beps, out, M, N, K);
}

// Round 5
// 631.720 us; speedup vs baseline: 1.1812x; 1.1812x over previous
//
#include <hip/hip_runtime.h>
#include <hip/hip_bf16.h>
#include <stdint.h>

typedef __bf16 bf16x8 __attribute__((ext_vector_type(8)));
typedef float f32x4 __attribute__((ext_vector_type(4)));
typedef unsigned short u16x8 __attribute__((ext_vector_type(8)));

// float -> bf16 round-to-nearest-even (bit trick; inputs are finite here)
__device__ inline unsigned short f2bf_rne(float f) {
  unsigned int u = __float_as_uint(f);
  u += 0x7fffu + ((u >> 16) & 1u);
  return (unsigned short)(u >> 16);
}

// w = mu + eps * exp(0.5*lv), packed bf16. 8 elems/thread, 16B store.
__global__ __launch_bounds__(256) void prep_weight(
    const float4* __restrict__ mu, const float4* __restrict__ lv,
    const float4* __restrict__ eps, u16x8* __restrict__ wbf, int n8) {
  int i = blockIdx.x * 256 + threadIdx.x;
  if (i >= n8) return;
  float4 m0 = mu[2 * i], m1 = mu[2 * i + 1];
  float4 v0 = lv[2 * i], v1 = lv[2 * i + 1];
  float4 e0 = eps[2 * i], e1 = eps[2 * i + 1];
  u16x8 p;
  p[0] = f2bf_rne(m0.x + e0.x * __expf(0.5f * v0.x));
  p[1] = f2bf_rne(m0.y + e0.y * __expf(0.5f * v0.y));
  p[2] = f2bf_rne(m0.z + e0.z * __expf(0.5f * v0.z));
  p[3] = f2bf_rne(m0.w + e0.w * __expf(0.5f * v0.w));
  p[4] = f2bf_rne(m1.x + e1.x * __expf(0.5f * v1.x));
  p[5] = f2bf_rne(m1.y + e1.y * __expf(0.5f * v1.y));
  p[6] = f2bf_rne(m1.z + e1.z * __expf(0.5f * v1.z));
  p[7] = f2bf_rne(m1.w + e1.w * __expf(0.5f * v1.w));
  wbf[i] = p;
}

__global__ __launch_bounds__(256) void prep_x(
    const float4* __restrict__ x, u16x8* __restrict__ xbf, int n8) {
  int i = blockIdx.x * 256 + threadIdx.x;
  if (i >= n8) return;
  float4 m0 = x[2 * i], m1 = x[2 * i + 1];
  u16x8 p;
  p[0] = f2bf_rne(m0.x); p[1] = f2bf_rne(m0.y);
  p[2] = f2bf_rne(m0.z); p[3] = f2bf_rne(m0.w);
  p[4] = f2bf_rne(m1.x); p[5] = f2bf_rne(m1.y);
  p[6] = f2bf_rne(m1.z); p[7] = f2bf_rne(m1.w);
  xbf[i] = p;
}

// C[M,N] = A[M,K]*B[N,K]^T + bias(N). 256x256 tile, BK=64, 512 thr = 8 waves
// (2M x 4N), per-wave output 128x64: acc[8][4], 64 MFMA/K-tile in 4 phases of
// 16 (Gray order over (mi-half, ni-half), both kk per phase).
// LDS 128KB: As[2][2][128*64], Bs[2][2][128*64] (buf x half), 128B rows with
// the R0/R4-verified zero-conflict XOR swizzle (granule g of row r holds
// global granule g^(r&7); read pg=((kk>>3)+gsel)^(mrow&7)).
// Phase = {ds_reads; stages; s_barrier; lgkmcnt(0); sched_barrier; setprio(1);
// 16 MFMA; setprio(0); s_barrier}.  Reads: P0 a-half0+b01(12), P1 a-half1(8),
// P2 b23(4), P3 none.  Stages: P2: A(t+2)->buf t&1 (WAR-safe: all A[c] frag
// reads certified complete by P1's 2nd barrier), P3: B(t+2)->buf t&1 (B[c]
// reads certified by P2's 2nd barrier).  ONE counted wait per K-tile at P3:
// vmcnt(8) retires tile t+1 (its 8 loads issued 4 phases earlier -> latency
// fully hidden); t+2's 8 loads stay in flight. Never drains to 0 mid-loop.
__global__ __launch_bounds__(512, 2) void gemm_bt_bias(
    const unsigned short* __restrict__ A,   // [M][K] bf16 bits
    const unsigned short* __restrict__ B,   // [N][K] bf16 bits
    const float* __restrict__ bmu, const float* __restrict__ blv,
    const float* __restrict__ beps,
    float* __restrict__ C, int M, int N, int K) {
  __shared__ __align__(16) unsigned short As[2][2][128 * 64];  // 64 KB
  __shared__ __align__(16) unsigned short Bs[2][2][128 * 64];  // 64 KB

  const int tid  = threadIdx.x;
  const int wave = tid >> 6;
  const int lane = tid & 63;
  const int wm = wave >> 2;   // 0..1  (M half)
  const int wn = wave & 3;    // 0..3  (N quarter)

  const int rowA0 = blockIdx.y * 256;
  const int rowB0 = blockIdx.x * 256;

  // staging: thread covers granule (tid&7) of row (tid>>3) per 64-row round;
  // global granule XOR-swizzled by row&7; LDS deposit linear (base+lane*16B).
  const int srow = tid >> 3;                       // 0..63
  const int scol = ((tid & 7) ^ (srow & 7)) * 8;
  const unsigned short* pA = A + (size_t)(rowA0 + srow) * K + scol;
  const unsigned short* pB = B + (size_t)(rowB0 + srow) * K + scol;
  const int dep = wave * 512;   // wave-uniform deposit base (elems) per round

#define GLL(srcp, dstp)                                                     \
  __builtin_amdgcn_global_load_lds(                                         \
      (const __attribute__((address_space(1))) unsigned int*)(srcp),        \
      (__attribute__((address_space(3))) unsigned int*)(dstp), 16, 0, 0)

  // half-tile stage: 128 rows x 64 K = 2 loads (rows 0-63, 64-127 of half h)
#define STAGE_A(kt, b, h) do {                                              \
    const unsigned short* s_ = pA + (size_t)((h) * 128) * K + (size_t)(kt) * 64; \
    GLL(s_, &As[b][h][dep]);                                                \
    GLL(s_ + (size_t)64 * K, &As[b][h][4096 + dep]); } while (0)
#define STAGE_B(kt, b, h) do {                                              \
    const unsigned short* s_ = pB + (size_t)((h) * 128) * K + (size_t)(kt) * 64; \
    GLL(s_, &Bs[b][h][dep]);                                                \
    GLL(s_ + (size_t)64 * K, &Bs[b][h][4096 + dep]); } while (0)

  f32x4 acc[8][4];
#pragma unroll
  for (int i = 0; i < 8; ++i)
#pragma unroll
    for (int j = 0; j < 4; ++j)
      acc[i][j] = (f32x4){0.f, 0.f, 0.f, 0.f};

  const int mrow = lane & 15;   // fragment row
  const int gsel = lane >> 4;   // k-granule select 0..3
  const int pgL = (gsel ^ (mrow & 7)) * 8;         // kk=0
  const int pgH = ((4 + gsel) ^ (mrow & 7)) * 8;   // kk=32
  const int aoff = mrow * 64;                      // + mi*1024 within half
  const int boff = ((wn & 1) * 64 + mrow) * 64;    // + ni*1024 within half

  // prologue: stage tiles 0 and 1 fully (16 loads); certify tile 0 only.
  STAGE_A(0, 0, 0); STAGE_A(0, 0, 1); STAGE_B(0, 0, 0); STAGE_B(0, 0, 1);
  STAGE_A(1, 1, 0); STAGE_A(1, 1, 1); STAGE_B(1, 1, 0); STAGE_B(1, 1, 1);
  asm volatile("s_waitcnt vmcnt(8)" ::: "memory");
  __builtin_amdgcn_s_barrier();
  __builtin_amdgcn_sched_barrier(0);

  bf16x8 a0[4][2], a1[4][2], b01[2][2], b23[2][2];

  const int NT = K / 64;
  for (int t = 0; t < NT; ++t) {
    const int c = t & 1;
    const unsigned short* as = &As[c][wm][0];
    const unsigned short* bs = &Bs[c][wn >> 1][0];
    const bool pf = (t + 2 < NT);

    // ---- P0: reads a-half0 (8) + b01 (4); MFMA (a0 x b01) ----
#pragma unroll
    for (int mi = 0; mi < 4; ++mi) {
      a0[mi][0] = *(const bf16x8*)&as[aoff + mi * 1024 + pgL];
      a0[mi][1] = *(const bf16x8*)&as[aoff + mi * 1024 + pgH];
    }
#pragma unroll
    for (int ni = 0; ni < 2; ++ni) {
      b01[ni][0] = *(const bf16x8*)&bs[boff + ni * 1024 + pgL];
      b01[ni][1] = *(const bf16x8*)&bs[boff + ni * 1024 + pgH];
    }
    __builtin_amdgcn_s_barrier();
    asm volatile("s_waitcnt lgkmcnt(0)" ::: "memory");
    __builtin_amdgcn_sched_barrier(0);
    __builtin_amdgcn_s_setprio(1);
#pragma unroll
    for (int kk = 0; kk < 2; ++kk)
#pragma unroll
      for (int mi = 0; mi < 4; ++mi)
#pragma unroll
        for (int ni = 0; ni < 2; ++ni)
          acc[mi][ni] = __builtin_amdgcn_mfma_f32_16x16x32_bf16(
              a0[mi][kk], b01[ni][kk], acc[mi][ni], 0, 0, 0);
    __builtin_amdgcn_s_setprio(0);
    __builtin_amdgcn_s_barrier();
    __builtin_amdgcn_sched_barrier(0);

    // ---- P1: reads a-half1 (8); MFMA (a1 x b01) ----
#pragma unroll
    for (int mi = 0; mi < 4; ++mi) {
      a1[mi][0] = *(const bf16x8*)&as[aoff + (mi + 4) * 1024 + pgL];
      a1[mi][1] = *(const bf16x8*)&as[aoff + (mi + 4) * 1024 + pgH];
    }
    __builtin_amdgcn_s_barrier();
    asm volatile("s_waitcnt lgkmcnt(0)" ::: "memory");
    __builtin_amdgcn_sched_barrier(0);
    __builtin_amdgcn_s_setprio(1);
#pragma unroll
    for (int kk = 0; kk < 2; ++kk)
#pragma unroll
      for (int mi = 0; mi < 4; ++mi)
#pragma unroll
        for (int ni = 0; ni < 2; ++ni)
          acc[mi + 4][ni] = __builtin_amdgcn_mfma_f32_16x16x32_bf16(
              a1[mi][kk], b01[ni][kk], acc[mi + 4][ni], 0, 0, 0);
    __builtin_amdgcn_s_setprio(0);
    __builtin_amdgcn_s_barrier();
    __builtin_amdgcn_sched_barrier(0);

    // ---- P2: reads b23 (4); stage A(t+2) -> buf c; MFMA (a1 x b23) ----
#pragma unroll
    for (int ni = 0; ni < 2; ++ni) {
      b23[ni][0] = *(const bf16x8*)&bs[boff + (ni + 2) * 1024 + pgL];
      b23[ni][1] = *(const bf16x8*)&bs[boff + (ni + 2) * 1024 + pgH];
    }
    if (pf) { STAGE_A(t + 2, c, 0); STAGE_A(t + 2, c, 1); }
    __builtin_amdgcn_s_barrier();
    asm volatile("s_waitcnt lgkmcnt(0)" ::: "memory");
    __builtin_amdgcn_sched_barrier(0);
    __builtin_amdgcn_s_setprio(1);
#pragma unroll
    for (int kk = 0; kk < 2; ++kk)
#pragma unroll
      for (int mi = 0; mi < 4; ++mi)
#pragma unroll
        for (int ni = 0; ni < 2; ++ni)
          acc[mi + 4][ni + 2] = __builtin_amdgcn_mfma_f32_16x16x32_bf16(
              a1[mi][kk], b23[ni][kk], acc[mi + 4][ni + 2], 0, 0, 0);
    __builtin_amdgcn_s_setprio(0);
    __builtin_amdgcn_s_barrier();
    __builtin_amdgcn_sched_barrier(0);

    // ---- P3: stage B(t+2) -> buf c; MFMA (a0 x b23); counted boundary ----
    if (pf) { STAGE_B(t + 2, c, 0); STAGE_B(t + 2, c, 1); }
    __builtin_amdgcn_s_barrier();
    __builtin_amdgcn_sched_barrier(0);
    __builtin_amdgcn_s_setprio(1);
#pragma unroll
    for (int kk = 0; kk < 2; ++kk)
#pragma unroll
      for (int mi = 0; mi < 4; ++mi)
#pragma unroll
        for (int ni = 0; ni < 2; ++ni)
          acc[mi][ni + 2] = __builtin_amdgcn_mfma_f32_16x16x32_bf16(
              a0[mi][kk], b23[ni][kk], acc[mi][ni + 2], 0, 0, 0);
    __builtin_amdgcn_s_setprio(0);
    if (t + 1 < NT) {
      if (pf) { asm volatile("s_waitcnt vmcnt(8)" ::: "memory"); }
      else    { asm volatile("s_waitcnt vmcnt(0)" ::: "memory"); }
    }
    __builtin_amdgcn_s_barrier();
    __builtin_amdgcn_sched_barrier(0);
  }

  // Epilogue: C/D layout col=lane&15, row=(lane>>4)*4+reg (m89-verified).
  const int colq = lane & 15;
  const int rq4  = (lane >> 4) * 4;
#pragma unroll
  for (int ni = 0; ni < 4; ++ni) {
    const int col = rowB0 + wn * 64 + ni * 16 + colq;
    const float bias = bmu[col] + beps[col] * __expf(0.5f * blv[col]);
#pragma unroll
    for (int mi = 0; mi < 8; ++mi) {
      const int rbase = rowA0 + wm * 128 + mi * 16 + rq4;
#pragma unroll
      for (int r = 0; r < 4; ++r)
        C[(size_t)(rbase + r) * N + col] = acc[mi][ni][r] + bias;
    }
  }
#undef GLL
#undef STAGE_A
#undef STAGE_B
}

extern "C" void kernel_launch(void* const* d_in, const int* in_sizes, int n_in,
                              void* d_out, int out_size, void* d_ws, size_t ws_size,
                              hipStream_t stream) {
  const float* x    = (const float*)d_in[0];
  const float* wmu  = (const float*)d_in[1];
  const float* wlv  = (const float*)d_in[2];
  const float* bmu  = (const float*)d_in[3];
  const float* blv  = (const float*)d_in[4];
  const float* weps = (const float*)d_in[5];
  const float* beps = (const float*)d_in[6];
  float* out = (float*)d_out;

  const int M = 8192, N = 4096, K = 4096;

  // workspace: xbf [M*K] bf16 (64 MB) then wbf [N*K] bf16 (32 MB)
  unsigned short* xbf = (unsigned short*)d_ws;
  unsigned short* wbf = xbf + (size_t)M * K;

  const int n8w = N * K / 8;
  prep_weight<<<n8w / 256, 256, 0, stream>>>(
      (const float4*)wmu, (const float4*)wlv, (const float4*)weps,
      (u16x8*)wbf, n8w);
  const int n8x = M * K / 8;
  prep_x<<<n8x / 256, 256, 0, stream>>>((const float4*)x, (u16x8*)xbf, n8x);

  dim3 grid(N / 256, M / 256);  // 16 x 32 = 512 blocks
  gemm_bt_bias<<<grid, 512, 0, stream>>>(xbf, wbf, bmu, blv, beps, out, M, N, K);
}